// Round 1
// baseline (855.582 us; speedup 1.0000x reference)
//
#include <hip/hip_runtime.h>

#define DEV __device__ __forceinline__

typedef __bf16 bf16x8 __attribute__((ext_vector_type(8)));
typedef float f32x4 __attribute__((ext_vector_type(4)));
typedef unsigned short u16;
typedef u16 u16x4 __attribute__((ext_vector_type(4)));

constexpr int T_ANS = 32768;        // N*La answer tokens
constexpr int LQ    = 64;
constexpr int M_ALL = T_ANS + LQ;   // 32832 rows fed to projection
constexpr int M_PAD = 32896;        // 257*128 (tile-padded)
constexpr int DIM   = 1024;

DEV u16 f2bf(float x) {
  unsigned u = __float_as_uint(x);
  return (u16)((u + 0x7FFFu + ((u >> 16) & 1u)) >> 16);
}
DEV float bf2f(u16 s) { return __uint_as_float(((unsigned)s) << 16); }

DEV void gl2lds16(const void* g, void* l) {
  __builtin_amdgcn_global_load_lds(
      (const __attribute__((address_space(1))) unsigned int*)g,
      (__attribute__((address_space(3))) unsigned int*)l, 16, 0, 0);
}

// ---------------- simple cast / gather kernels ----------------

__global__ void cast4(const float* __restrict__ src, u16* __restrict__ dst, int n4) {
  int i = blockIdx.x * 256 + threadIdx.x;
  if (i < n4) {
    float4 v = ((const float4*)src)[i];
    u16x4 o = { f2bf(v.x), f2bf(v.y), f2bf(v.z), f2bf(v.w) };
    ((u16x4*)dst)[i] = o;
  }
}

// cw[o][i][k] (stride W in k) -> W matrices BT_k[o][i], k-major contiguous reads
template<int W>
__global__ void cast_conv_w(const float* __restrict__ src, u16* __restrict__ dst) {
  int i = blockIdx.x * 256 + threadIdx.x;  // over 1024*1024
  if (i < 1024 * 1024) {
#pragma unroll
    for (int k = 0; k < W; ++k)
      dst[(size_t)k * (1024 * 1024) + i] = f2bf(src[(size_t)i * W + k]);
  }
}

__global__ void gather_cast(const int* __restrict__ dq, const int* __restrict__ das,
                            const float* __restrict__ emb, u16* __restrict__ X) {
  const int row = blockIdx.x;        // [0, M_PAD)
  const int c   = threadIdx.x;       // 256 threads * 4 floats = 1024
  size_t dsto = (size_t)row * DIM + c * 4;
  if (row >= M_ALL) {                // zero pad rows so GEMM tiles are clean
    u16x4 z = {0, 0, 0, 0};
    *(u16x4*)(X + dsto) = z;
    return;
  }
  const int tok = (row < T_ANS) ? das[row] : dq[row - T_ANS];
  float4 v = ((const float4*)(emb + (size_t)tok * DIM))[c];
  u16x4 o = { f2bf(v.x), f2bf(v.y), f2bf(v.z), f2bf(v.w) };
  *(u16x4*)(X + dsto) = o;
}

__global__ void transpose_pq(const u16* __restrict__ pa, u16* __restrict__ pqT) {
  int i = blockIdx.x * 256 + threadIdx.x;  // 1024*64
  int e = i >> 6, q = i & 63;
  pqT[i] = pa[(size_t)(T_ANS + q) * DIM + e];
}

__global__ void zero_pad_sim(u16* __restrict__ sim) {
  int i = blockIdx.x * 256 + threadIdx.x;
  if (i < 2 * DIM) sim[(size_t)T_ANS * DIM + i] = 0;
}

__global__ void cast_cat(const float* __restrict__ cat, u16* __restrict__ catb) {
  int i = blockIdx.x * 256 + threadIdx.x;  // 128*3072
  if (i < 128 * 3072) {
    int row = i / 3072;
    catb[i] = (row < 64) ? f2bf(cat[i]) : (u16)0;
  }
}

// ---------------- projection: pa = sigmoid(X@w1^T+b1)*tanh(X@w2^T+b2) ----------------

__global__ __launch_bounds__(256, 2)
void proj_dual(const u16* __restrict__ X, const u16* __restrict__ B1,
               const u16* __restrict__ B2, const float* __restrict__ b1,
               const float* __restrict__ b2, u16* __restrict__ pa) {
  __shared__ alignas(16) u16 sA[128 * 32];
  __shared__ alignas(16) u16 sB1[128 * 32];
  __shared__ alignas(16) u16 sB2[128 * 32];
  const int tid = threadIdx.x, lane = tid & 63;
  const int tm = blockIdx.x * 128, tn = blockIdx.y * 128;
  const int wid = tid >> 6;
  const int wm = (wid >> 1) * 64, wn = (wid & 1) * 64;
  f32x4 acc1[4][4] = {}, acc2[4][4] = {};
  for (int k0 = 0; k0 < 1024; k0 += 32) {
#pragma unroll
    for (int j = 0; j < 2; ++j) {
      const int f = tid * 16 + j * 4096;
      const int r = f >> 6, cb = f & 63;
      gl2lds16((const char*)X  + (size_t)(tm + r) * 2048 + k0 * 2 + cb, (char*)sA  + f);
      gl2lds16((const char*)B1 + (size_t)(tn + r) * 2048 + k0 * 2 + cb, (char*)sB1 + f);
      gl2lds16((const char*)B2 + (size_t)(tn + r) * 2048 + k0 * 2 + cb, (char*)sB2 + f);
    }
    __syncthreads();
    const int lr = lane & 15, lk = (lane >> 4) * 8;
    bf16x8 af[4], bf1[4], bf2[4];
#pragma unroll
    for (int i = 0; i < 4; ++i) {
      af[i]  = *(const bf16x8*)(sA  + (wm + i * 16 + lr) * 32 + lk);
      bf1[i] = *(const bf16x8*)(sB1 + (wn + i * 16 + lr) * 32 + lk);
      bf2[i] = *(const bf16x8*)(sB2 + (wn + i * 16 + lr) * 32 + lk);
    }
#pragma unroll
    for (int mi = 0; mi < 4; ++mi)
#pragma unroll
      for (int ni = 0; ni < 4; ++ni) {
        acc1[mi][ni] = __builtin_amdgcn_mfma_f32_16x16x32_bf16(af[mi], bf1[ni], acc1[mi][ni], 0, 0, 0);
        acc2[mi][ni] = __builtin_amdgcn_mfma_f32_16x16x32_bf16(af[mi], bf2[ni], acc2[mi][ni], 0, 0, 0);
      }
    __syncthreads();
  }
  const int lr = lane & 15, lg = (lane >> 4) * 4;
#pragma unroll
  for (int ni = 0; ni < 4; ++ni) {
    const int col = tn + wn + ni * 16 + lr;
    const float b1v = b1[col], b2v = b2[col];
#pragma unroll
    for (int mi = 0; mi < 4; ++mi)
#pragma unroll
      for (int r = 0; r < 4; ++r) {
        const int row = tm + wm + mi * 16 + lg + r;
        const float x1 = acc1[mi][ni][r] + b1v;
        const float x2 = acc2[mi][ni][r] + b2v;
        const float sg = 1.f / (1.f + __expf(-x1));
        const float th = 2.f / (1.f + __expf(-2.f * x2)) - 1.f;
        pa[(size_t)row * DIM + col] = f2bf(sg * th);
      }
  }
}

// ---------------- attention S = pa @ pq^T  (N=64 tile) ----------------

__global__ __launch_bounds__(256, 2)
void attn_s(const u16* __restrict__ pa, float* __restrict__ S) {
  __shared__ alignas(16) u16 sA[128 * 32];
  __shared__ alignas(16) u16 sB[64 * 32];
  const int tid = threadIdx.x, lane = tid & 63;
  const int tm = blockIdx.x * 128;
  const int wid = tid >> 6;
  const int wm = (wid >> 1) * 64, wn = (wid & 1) * 32;
  const u16* pq = pa + (size_t)T_ANS * DIM;
  f32x4 acc[4][2] = {};
  for (int k0 = 0; k0 < 1024; k0 += 32) {
#pragma unroll
    for (int j = 0; j < 2; ++j) {
      const int f = tid * 16 + j * 4096;
      const int r = f >> 6, cb = f & 63;
      gl2lds16((const char*)pa + (size_t)(tm + r) * 2048 + k0 * 2 + cb, (char*)sA + f);
    }
    {
      const int f = tid * 16;  // 4 KB, single issue
      const int r = f >> 6, cb = f & 63;
      gl2lds16((const char*)pq + (size_t)r * 2048 + k0 * 2 + cb, (char*)sB + f);
    }
    __syncthreads();
    const int lr = lane & 15, lk = (lane >> 4) * 8;
    bf16x8 af[4], bfr[2];
#pragma unroll
    for (int i = 0; i < 4; ++i)
      af[i] = *(const bf16x8*)(sA + (wm + i * 16 + lr) * 32 + lk);
#pragma unroll
    for (int i = 0; i < 2; ++i)
      bfr[i] = *(const bf16x8*)(sB + (wn + i * 16 + lr) * 32 + lk);
#pragma unroll
    for (int mi = 0; mi < 4; ++mi)
#pragma unroll
      for (int ni = 0; ni < 2; ++ni)
        acc[mi][ni] = __builtin_amdgcn_mfma_f32_16x16x32_bf16(af[mi], bfr[ni], acc[mi][ni], 0, 0, 0);
    __syncthreads();
  }
  const int lr = lane & 15, lg = (lane >> 4) * 4;
#pragma unroll
  for (int mi = 0; mi < 4; ++mi)
#pragma unroll
    for (int ni = 0; ni < 2; ++ni)
#pragma unroll
      for (int r = 0; r < 4; ++r) {
        const int row = tm + wm + mi * 16 + lg + r;
        const int col = wn + ni * 16 + lr;
        S[(size_t)row * 64 + col] = acc[mi][ni][r];
      }
}

__global__ void softmax64(const float* __restrict__ S, u16* __restrict__ alpha) {
  const int row = blockIdx.x * 4 + (threadIdx.x >> 6);
  const int lane = threadIdx.x & 63;
  const float v = S[(size_t)row * 64 + lane];
  float m = v;
#pragma unroll
  for (int o = 32; o > 0; o >>= 1) m = fmaxf(m, __shfl_xor(m, o));
  const float e = __expf(v - m);
  float s = e;
#pragma unroll
  for (int o = 32; o > 0; o >>= 1) s += __shfl_xor(s, o);
  alpha[(size_t)row * 64 + lane] = f2bf(e / s);
}

// ---------------- Y = alpha @ pq ; sim = pa * Y ----------------

__global__ __launch_bounds__(256, 2)
void attn_y_sim(const u16* __restrict__ alpha, const u16* __restrict__ pqT,
                const u16* __restrict__ pa, u16* __restrict__ sim) {
  __shared__ alignas(16) u16 sA[128 * 32];
  __shared__ alignas(16) u16 sB[128 * 32];
  const int tid = threadIdx.x, lane = tid & 63;
  const int tm = blockIdx.x * 128, tn = blockIdx.y * 128;
  const int wid = tid >> 6;
  const int wm = (wid >> 1) * 64, wn = (wid & 1) * 64;
  f32x4 acc[4][4] = {};
  for (int k0 = 0; k0 < 64; k0 += 32) {
#pragma unroll
    for (int j = 0; j < 2; ++j) {
      const int f = tid * 16 + j * 4096;
      const int r = f >> 6, cb = f & 63;
      gl2lds16((const char*)alpha + (size_t)(tm + r) * 128 + k0 * 2 + cb, (char*)sA + f);
      gl2lds16((const char*)pqT   + (size_t)(tn + r) * 128 + k0 * 2 + cb, (char*)sB + f);
    }
    __syncthreads();
    const int lr = lane & 15, lk = (lane >> 4) * 8;
    bf16x8 af[4], bfr[4];
#pragma unroll
    for (int i = 0; i < 4; ++i) {
      af[i]  = *(const bf16x8*)(sA + (wm + i * 16 + lr) * 32 + lk);
      bfr[i] = *(const bf16x8*)(sB + (wn + i * 16 + lr) * 32 + lk);
    }
#pragma unroll
    for (int mi = 0; mi < 4; ++mi)
#pragma unroll
      for (int ni = 0; ni < 4; ++ni)
        acc[mi][ni] = __builtin_amdgcn_mfma_f32_16x16x32_bf16(af[mi], bfr[ni], acc[mi][ni], 0, 0, 0);
    __syncthreads();
  }
  const int lr = lane & 15, lg = (lane >> 4) * 4;
#pragma unroll
  for (int ni = 0; ni < 4; ++ni) {
    const int col = tn + wn + ni * 16 + lr;
#pragma unroll
    for (int mi = 0; mi < 4; ++mi)
#pragma unroll
      for (int r = 0; r < 4; ++r) {
        const int row = tm + wm + mi * 16 + lg + r;
        const size_t o = (size_t)row * DIM + col;
        sim[o] = f2bf(bf2f(pa[o]) * acc[mi][ni][r]);
      }
  }
}

// ---------------- conv (window W) + relu + per-answer DMax ----------------

template<int W>
__global__ __launch_bounds__(256, 2)
void conv_pool(const u16* __restrict__ sim, const u16* __restrict__ Bw,
               const float* __restrict__ cb, float* __restrict__ cat) {
  __shared__ alignas(16) u16 sA[(128 + W) * 32];
  __shared__ alignas(16) u16 sB[W][128 * 32];
  const int tid = threadIdx.x, lane = tid & 63;
  const int tm = blockIdx.x * 128, tn = blockIdx.y * 128;
  const int wid = tid >> 6;
  const int wm = (wid >> 1) * 64, wn = (wid & 1) * 64;
  f32x4 acc[4][4] = {};
  for (int k0 = 0; k0 < 1024; k0 += 32) {
#pragma unroll
    for (int j = 0; j < 2; ++j) {
      const int f = tid * 16 + j * 4096;
      const int r = f >> 6, cbo = f & 63;
      gl2lds16((const char*)sim + (size_t)(tm + r) * 2048 + k0 * 2 + cbo, (char*)sA + f);
#pragma unroll
      for (int k = 0; k < W; ++k)
        gl2lds16((const char*)Bw + (size_t)k * 2097152 + (size_t)(tn + r) * 2048 + k0 * 2 + cbo,
                 (char*)&sB[k][0] + f);
    }
    if (W > 1 && tid < (W - 1) * 4) {   // extra A rows 128..128+W-2 (wave 0, lanes 0..)
      const int f = 8192 + tid * 16;
      const int r = f >> 6, cbo = f & 63;
      gl2lds16((const char*)sim + (size_t)(tm + r) * 2048 + k0 * 2 + cbo, (char*)sA + f);
    }
    __syncthreads();
    const int lr = lane & 15, lk = (lane >> 4) * 8;
#pragma unroll
    for (int k = 0; k < W; ++k) {
      bf16x8 af[4], bfr[4];
#pragma unroll
      for (int i = 0; i < 4; ++i) {
        af[i]  = *(const bf16x8*)(sA + (wm + i * 16 + lr + k) * 32 + lk);
        bfr[i] = *(const bf16x8*)(&sB[k][0] + (wn + i * 16 + lr) * 32 + lk);
      }
#pragma unroll
      for (int mi = 0; mi < 4; ++mi)
#pragma unroll
        for (int ni = 0; ni < 4; ++ni)
          acc[mi][ni] = __builtin_amdgcn_mfma_f32_16x16x32_bf16(af[mi], bfr[ni], acc[mi][ni], 0, 0, 0);
    }
    __syncthreads();
  }
  // epilogue: +cb, relu, mask boundary rows, column max, atomicMax into cat
  const int lr = lane & 15, lg = (lane >> 4) * 4;
  const int n = tm >> 9;  // 128 | 512 so one answer per tile
#pragma unroll
  for (int ni = 0; ni < 4; ++ni) {
    const int col = tn + wn + ni * 16 + lr;
    const float cbv = cb[col];
    float vmax = 0.f;
#pragma unroll
    for (int mi = 0; mi < 4; ++mi)
#pragma unroll
      for (int r = 0; r < 4; ++r) {
        const int t = tm + wm + mi * 16 + lg + r;
        float v = fmaxf(acc[mi][ni][r] + cbv, 0.f);
        if ((t & 511) > 512 - W) v = 0.f;  // window straddles answer boundary
        vmax = fmaxf(vmax, v);
      }
    vmax = fmaxf(vmax, __shfl_xor(vmax, 16));
    vmax = fmaxf(vmax, __shfl_xor(vmax, 32));
    if (lane < 16)
      atomicMax((int*)&cat[(size_t)n * 3072 + (W - 1) * 1024 + col], __float_as_int(vmax));
  }
}

// ---------------- final: h = tanh(cat @ lin^T + b) ----------------

__global__ __launch_bounds__(256, 2)
void final_h(const u16* __restrict__ catb, const u16* __restrict__ linb,
             const float* __restrict__ lin_b, float* __restrict__ h) {
  __shared__ alignas(16) u16 sA[128 * 32];
  __shared__ alignas(16) u16 sB[128 * 32];
  const int tid = threadIdx.x, lane = tid & 63;
  const int tn = blockIdx.y * 128;
  const int wid = tid >> 6;
  const int wm = (wid >> 1) * 64, wn = (wid & 1) * 64;
  f32x4 acc[4][4] = {};
  for (int k0 = 0; k0 < 3072; k0 += 32) {
#pragma unroll
    for (int j = 0; j < 2; ++j) {
      const int f = tid * 16 + j * 4096;
      const int r = f >> 6, cb = f & 63;
      gl2lds16((const char*)catb + (size_t)r * 6144 + k0 * 2 + cb, (char*)sA + f);
      gl2lds16((const char*)linb + (size_t)(tn + r) * 6144 + k0 * 2 + cb, (char*)sB + f);
    }
    __syncthreads();
    const int lr = lane & 15, lk = (lane >> 4) * 8;
    bf16x8 af[4], bfr[4];
#pragma unroll
    for (int i = 0; i < 4; ++i) {
      af[i]  = *(const bf16x8*)(sA + (wm + i * 16 + lr) * 32 + lk);
      bfr[i] = *(const bf16x8*)(sB + (wn + i * 16 + lr) * 32 + lk);
    }
#pragma unroll
    for (int mi = 0; mi < 4; ++mi)
#pragma unroll
      for (int ni = 0; ni < 4; ++ni)
        acc[mi][ni] = __builtin_amdgcn_mfma_f32_16x16x32_bf16(af[mi], bfr[ni], acc[mi][ni], 0, 0, 0);
    __syncthreads();
  }
  const int lr = lane & 15, lg = (lane >> 4) * 4;
#pragma unroll
  for (int ni = 0; ni < 4; ++ni) {
    const int col = tn + wn + ni * 16 + lr;
    const float bv = lin_b[col];
#pragma unroll
    for (int mi = 0; mi < 4; ++mi)
#pragma unroll
      for (int r = 0; r < 4; ++r) {
        const int row = wm + mi * 16 + lg + r;
        if (row < 64) {
          const float x = acc[mi][ni][r] + bv;
          h[(size_t)row * DIM + col] = 2.f / (1.f + __expf(-2.f * x)) - 1.f;
        }
      }
  }
}

__global__ void final_logits(const float* __restrict__ h, const float* __restrict__ soft_w,
                             const float* __restrict__ soft_b, float* __restrict__ out) {
  __shared__ float part[256];
  const int t = threadIdx.x;
  const int n = t >> 2, q = t & 3;
  float s = 0.f;
  for (int j = q * 256; j < q * 256 + 256; ++j) s += h[(size_t)n * DIM + j] * soft_w[j];
  part[t] = s;
  __syncthreads();
  if (t < 64) {
    float logit = part[t * 4] + part[t * 4 + 1] + part[t * 4 + 2] + part[t * 4 + 3] + soft_b[0];
    float m = logit;
#pragma unroll
    for (int o = 32; o > 0; o >>= 1) m = fmaxf(m, __shfl_xor(m, o));
    float e = __expf(logit - m);
    float ssum = e;
#pragma unroll
    for (int o = 32; o > 0; o >>= 1) ssum += __shfl_xor(ssum, o);
    out[t] = (logit - m) - logf(ssum);
  }
}

// ---------------- launcher ----------------

extern "C" void kernel_launch(void* const* d_in, const int* in_sizes, int n_in,
                              void* d_out, int out_size, void* d_ws, size_t ws_size,
                              hipStream_t stream) {
  const int*   data_q  = (const int*)d_in[0];
  const int*   data_as = (const int*)d_in[1];
  const float* emb     = (const float*)d_in[2];
  const float* w1      = (const float*)d_in[3];
  const float* b1      = (const float*)d_in[4];
  const float* w2      = (const float*)d_in[5];
  const float* b2      = (const float*)d_in[6];
  const float* cw1     = (const float*)d_in[7];
  const float* cb1     = (const float*)d_in[8];
  const float* cw2     = (const float*)d_in[9];
  const float* cb2     = (const float*)d_in[10];
  const float* cw3     = (const float*)d_in[11];
  const float* cb3     = (const float*)d_in[12];
  const float* lin_w   = (const float*)d_in[13];
  const float* lin_b   = (const float*)d_in[14];
  const float* soft_w  = (const float*)d_in[15];
  const float* soft_b  = (const float*)d_in[16];
  float* out = (float*)d_out;

  // workspace layout (~172.4 MB total)
  u16* X     = (u16*)d_ws;                         // [M_PAD][1024] bf16; later reused as sim
  u16* pa    = X    + (size_t)M_PAD * DIM;         // [M_PAD][1024] bf16 (rows T..T+63 = pq)
  u16* w1b   = pa   + (size_t)M_PAD * DIM;         // [1024][1024]
  u16* w2b   = w1b  + 1024 * 1024;
  u16* cwb   = w2b  + 1024 * 1024;                 // 6 x [1024][1024]
  u16* linb  = cwb  + (size_t)6 * 1024 * 1024;     // [1024][3072]
  u16* pqT   = linb + (size_t)3 * 1024 * 1024;     // [1024][64]
  u16* alpha = pqT  + 64 * 1024;                   // [T][64] bf16
  float* S   = (float*)(alpha + (size_t)T_ANS * 64);  // [T][64] f32
  float* cat = S + (size_t)T_ANS * 64;             // [64][3072] f32 pools
  u16* catb  = (u16*)(cat + 64 * 3072);            // [128][3072] bf16 (rows 64+ zero)
  float* h   = (float*)(catb + 128 * 3072);        // [64][1024] f32
  u16* simb  = X;                                  // alias: [T+2][1024] bf16

  hipMemsetAsync(cat, 0, 64 * 3072 * sizeof(float), stream);

  cast4<<<1024, 256, 0, stream>>>(w1, w1b, 1024 * 1024 / 4);
  cast4<<<1024, 256, 0, stream>>>(w2, w2b, 1024 * 1024 / 4);
  cast4<<<3072, 256, 0, stream>>>(lin_w, linb, 3072 * 1024 / 4);
  cast_conv_w<1><<<4096, 256, 0, stream>>>(cw1, cwb);
  cast_conv_w<2><<<4096, 256, 0, stream>>>(cw2, cwb + (size_t)1 * 1024 * 1024);
  cast_conv_w<3><<<4096, 256, 0, stream>>>(cw3, cwb + (size_t)3 * 1024 * 1024);

  gather_cast<<<M_PAD, 256, 0, stream>>>(data_q, data_as, emb, X);

  proj_dual<<<dim3(M_PAD / 128, 8), 256, 0, stream>>>(X, w1b, w2b, b1, b2, pa);
  transpose_pq<<<256, 256, 0, stream>>>(pa, pqT);

  attn_s<<<T_ANS / 128, 256, 0, stream>>>(pa, S);
  softmax64<<<T_ANS / 4, 256, 0, stream>>>(S, alpha);
  attn_y_sim<<<dim3(T_ANS / 128, 8), 256, 0, stream>>>(alpha, pqT, pa, simb);
  zero_pad_sim<<<8, 256, 0, stream>>>(simb);

  conv_pool<1><<<dim3(T_ANS / 128, 8), 256, 0, stream>>>(simb, cwb, cb1, cat);
  conv_pool<2><<<dim3(T_ANS / 128, 8), 256, 0, stream>>>(simb, cwb + (size_t)1 * 1024 * 1024, cb2, cat);
  conv_pool<3><<<dim3(T_ANS / 128, 8), 256, 0, stream>>>(simb, cwb + (size_t)3 * 1024 * 1024, cb3, cat);

  cast_cat<<<1536, 256, 0, stream>>>(cat, catb);
  final_h<<<dim3(1, 8), 256, 0, stream>>>(catb, linb, lin_b, h);
  final_logits<<<1, 256, 0, stream>>>(h, soft_w, soft_b, out);
}